// Round 9
// baseline (476.301 us; speedup 1.0000x reference)
//
#include <hip/hip_runtime.h>
#include <hip/hip_bf16.h>
#include <cstdint>
#include <cstddef>

// Problem constants (from reference): N=50000, E=800000, IN=512, HID=256, MID=128, OUT=64
#define F_IN  512
#define F_HID 256
#define F_MID 128
#define F_OUT 64

typedef __attribute__((ext_vector_type(8))) short short8;   // 8 x bf16 (4 VGPRs)
typedef __attribute__((ext_vector_type(4))) float floatx4;  // MFMA accumulator

static __device__ __forceinline__ float b2f(ushort u) {
  union { unsigned u; float f; } v; v.u = ((unsigned)u) << 16; return v.f;
}
static __device__ __forceinline__ ushort f2b(float f) {
  union { float f; unsigned u; } v; v.f = f;
  unsigned r = v.u + 0x7fffu + ((v.u >> 16) & 1u);  // round-to-nearest-even
  return (ushort)(r >> 16);
}
// 8x f32 -> 8x bf16 via packed v_cvt_pk_bf16_f32 (RNE)
static __device__ __forceinline__ short8 cvt8(float4 lo, float4 hi) {
  union { __hip_bfloat162 h[4]; short8 s; } r;
  r.h[0] = __float22bfloat162_rn({lo.x, lo.y});
  r.h[1] = __float22bfloat162_rn({lo.z, lo.w});
  r.h[2] = __float22bfloat162_rn({hi.x, hi.y});
  r.h[3] = __float22bfloat162_rn({hi.z, hi.w});
  return r.s;
}

// ---------------- CSR build ----------------

__global__ __launch_bounds__(256) void hist_kernel(const int* __restrict__ dst,
                                                   int* __restrict__ cnt, int e) {
  int i = blockIdx.x * 256 + threadIdx.x;
  if (i < e) atomicAdd(&cnt[dst[i]], 1);
}

// per-block exclusive scan + block partial; also computes dinv and zeroes cnt (cursor reuse).
// rp[i] written for i<=n (relative to block); absolute offset = rp[i] + part[i>>10].
__global__ __launch_bounds__(1024) void scan1_kernel(int* __restrict__ cnt,
                                                     int* __restrict__ rp,
                                                     int* __restrict__ part,
                                                     float* __restrict__ dinv, int n) {
  __shared__ int buf[1024];
  int tid = threadIdx.x;
  int i = blockIdx.x * 1024 + tid;
  int v = (i < n) ? cnt[i] : 0;
  if (i < n) { dinv[i] = rsqrtf(1.0f + (float)v); cnt[i] = 0; }
  buf[tid] = v;
  __syncthreads();
  for (int off = 1; off < 1024; off <<= 1) {
    int t = (tid >= off) ? buf[tid - off] : 0;
    __syncthreads();
    buf[tid] += t;
    __syncthreads();
  }
  if (i <= n) rp[i] = buf[tid] - v;          // exclusive, block-relative
  if (tid == 1023) part[blockIdx.x] = buf[1023];
}

// exclusive scan of block partials (nb <= 1024), in place
__global__ __launch_bounds__(1024) void scan2_kernel(int* __restrict__ part, int nb) {
  __shared__ int buf[1024];
  int tid = threadIdx.x;
  int v = (tid < nb) ? part[tid] : 0;
  buf[tid] = v;
  __syncthreads();
  for (int off = 1; off < 1024; off <<= 1) {
    int t = (tid >= off) ? buf[tid - off] : 0;
    __syncthreads();
    buf[tid] += t;
    __syncthreads();
  }
  if (tid < nb) part[tid] = buf[tid] - v;
}

__global__ __launch_bounds__(256) void fill_kernel(const int* __restrict__ src,
                                                   const int* __restrict__ dst,
                                                   const int* __restrict__ rp,
                                                   const int* __restrict__ part,
                                                   int* __restrict__ cur,
                                                   int* __restrict__ srcs, int e) {
  int i = blockIdx.x * 256 + threadIdx.x;
  if (i < e) {
    int d = dst[i];
    int p = rp[d] + part[d >> 10] + atomicAdd(&cur[d], 1);
    srcs[p] = src[i];
  }
}

// all three weight transposes in one launch: W (f32 [K][F]) -> WT (bf16 [F][K])
__global__ __launch_bounds__(256) void transpose_all(const float* __restrict__ W1,
                                                     const float* __restrict__ W2,
                                                     const float* __restrict__ Wc,
                                                     ushort* __restrict__ w1t,
                                                     ushort* __restrict__ w2t,
                                                     ushort* __restrict__ wct) {
  int i = blockIdx.x * 256 + threadIdx.x;
  if (i < F_IN * F_HID) {
    int k = i / F_HID, f = i % F_HID;
    w1t[(size_t)f * F_IN + k] = f2b(W1[i]);
    return;
  }
  int j = i - F_IN * F_HID;
  if (j < F_HID * F_MID) {
    int k = j / F_MID, f = j % F_MID;
    w2t[(size_t)f * F_HID + k] = f2b(W2[j]);
    return;
  }
  int l = j - F_HID * F_MID;
  if (l < F_MID * F_OUT) {
    int k = l / F_OUT, f = l % F_OUT;
    wct[(size_t)f * F_MID + k] = f2b(Wc[l]);
  }
}

// ---------------- Register-direct MFMA GEMM: C[M,F] = A[M,K]*B[K,F], BT bf16 [F][K] ----------
// NO LDS, NO barriers. Each wave owns a 64x64 tile: A and B fragments are loaded DIRECTLY
// from global memory in MFMA register layout (per instr: 16 rows x 64B contiguous -> fully
// coalesced; B lines shared by the block's 4 waves dedupe in L1; B L2 traffic ~200MB is cheap).
// Rationale: rounds 3-8 proved every LDS-staged K-loop serializes at 70-95us — compiler emits
// fetch -> vmcnt(0) -> ds_write each iter (VGPR_Count=44 proves no cross-iter pipelining).
// Straight-line unrolled barrier-free code lets the compiler's fine-grained vmcnt(N)
// scheduling actually pipeline. Block = 4 waves = 4 row-tiles (256 rows), one 64-col panel.
// LSM: fuse log_softmax into the epilogue (wave holds complete 64-wide rows when F==64).
template<int K, bool A_F32, bool OUT_F32, bool LSM>
__global__ __launch_bounds__(256) void gemm_reg(const void* __restrict__ Av,
                                                const ushort* __restrict__ BT,
                                                const float* __restrict__ bias,
                                                void* __restrict__ Cv,
                                                int M, int F) {
  const int lane = threadIdx.x & 63, wv = threadIdx.x >> 6;
  const int q = lane >> 4, ml = lane & 15;
  const int bn = blockIdx.y << 6;
  const int rbase = (blockIdx.x * 4 + wv) << 6;

  int ri[4];
#pragma unroll
  for (int i = 0; i < 4; i++) ri[i] = min(rbase + 16 * i + ml, M - 1);
  const ushort* bp[4];
#pragma unroll
  for (int j = 0; j < 4; j++) bp[j] = BT + (size_t)(bn + 16 * j + ml) * K;

  floatx4 acc[4][4] = {};

#pragma unroll
  for (int c = 0; c < K / 32; c++) {
    const int kk = c * 32 + q * 8;
    short8 a[4], b[4];
    if (A_F32) {
      const float* A = (const float*)Av;
#pragma unroll
      for (int i = 0; i < 4; i++) {
        float4 lo = *(const float4*)(A + (size_t)ri[i] * K + kk);
        float4 hi = *(const float4*)(A + (size_t)ri[i] * K + kk + 4);
        a[i] = cvt8(lo, hi);
      }
    } else {
      const ushort* A = (const ushort*)Av;
#pragma unroll
      for (int i = 0; i < 4; i++) a[i] = *(const short8*)(A + (size_t)ri[i] * K + kk);
    }
#pragma unroll
    for (int j = 0; j < 4; j++) b[j] = *(const short8*)(bp[j] + kk);
#pragma unroll
    for (int i = 0; i < 4; i++)
#pragma unroll
      for (int j = 0; j < 4; j++)
        acc[i][j] = __builtin_amdgcn_mfma_f32_16x16x32_bf16(a[i], b[j], acc[i][j], 0, 0, 0);
  }

  // epilogue: C/D col = lane&15, row = quad*4 + reg [m89 verified]
  float bj[4];
#pragma unroll
  for (int j = 0; j < 4; j++) bj[j] = bias ? bias[bn + 16 * j + ml] : 0.0f;

  if (LSM) {
    // F == 64: this wave holds complete rows. Row r=(16i+q*4+rr): its 64 cols live in
    // acc[i][0..3][rr] across the 16 lanes sharing q -> reduce with shfl_xor over ml bits.
#pragma unroll
    for (int i = 0; i < 4; i++) {
#pragma unroll
      for (int rr = 0; rr < 4; rr++) {
        float vv[4];
#pragma unroll
        for (int j = 0; j < 4; j++) vv[j] = acc[i][j][rr] + bj[j];
        float mx = fmaxf(fmaxf(vv[0], vv[1]), fmaxf(vv[2], vv[3]));
#pragma unroll
        for (int off = 1; off <= 8; off <<= 1) mx = fmaxf(mx, __shfl_xor(mx, off, 64));
        float s = __expf(vv[0] - mx) + __expf(vv[1] - mx) +
                  __expf(vv[2] - mx) + __expf(vv[3] - mx);
#pragma unroll
        for (int off = 1; off <= 8; off <<= 1) s += __shfl_xor(s, off, 64);
        float lg = mx + __logf(s);
        int m = rbase + 16 * i + q * 4 + rr;
        if (m < M) {
#pragma unroll
          for (int j = 0; j < 4; j++)
            ((float*)Cv)[(size_t)m * F + bn + 16 * j + ml] = vv[j] - lg;
        }
      }
    }
  } else {
#pragma unroll
    for (int j = 0; j < 4; j++) {
      int n = bn + 16 * j + ml;
#pragma unroll
      for (int i = 0; i < 4; i++) {
#pragma unroll
        for (int rr = 0; rr < 4; rr++) {
          int m = rbase + 16 * i + q * 4 + rr;
          if (m < M) {
            float val = acc[i][j][rr] + bj[j];
            if (OUT_F32) ((float*)Cv)[(size_t)m * F + n] = val;
            else         ((ushort*)Cv)[(size_t)m * F + n] = f2b(val);
          }
        }
      }
    }
  }
}

// ---------------- GCN aggregation: out[d] = relu(b + dinv_d^2*H[d] + sum_e dinv_s*dinv_d*H[s]) ----------------
// one wave per destination node; lane holds F/64 contiguous features. H bf16, out bf16, bias f32.
// Edge loop unrolled x8: ~17 outstanding VMEM ops/wave. CSR offsets = rp[.] + part[.>>10].
template<int F>
__global__ __launch_bounds__(256) void agg_kernel(const ushort* __restrict__ H,
                                                  const float* __restrict__ bias,
                                                  const float* __restrict__ dinv,
                                                  const int* __restrict__ rp,
                                                  const int* __restrict__ part,
                                                  const int* __restrict__ srcs,
                                                  ushort* __restrict__ out, int n) {
  constexpr int VPL = F / 64;
  int wid = blockIdx.x * 4 + (threadIdx.x >> 6);
  if (wid >= n) return;
  int lane = threadIdx.x & 63;
  int fo = lane * VPL;
  const ushort* Hf = H + fo;
  float invd = dinv[wid];
  float acc[VPL];
#pragma unroll
  for (int v = 0; v < VPL; v++) acc[v] = bias[fo + v];
  {
    float ws = invd * invd;
    if (VPL == 4) {
      ushort4 hv = *(const ushort4*)(Hf + (size_t)wid * F);
      acc[0] += ws * b2f(hv.x); acc[1] += ws * b2f(hv.y);
      acc[2] += ws * b2f(hv.z); acc[3] += ws * b2f(hv.w);
    } else {
      ushort2 hv = *(const ushort2*)(Hf + (size_t)wid * F);
      acc[0] += ws * b2f(hv.x); acc[1] += ws * b2f(hv.y);
    }
  }
  int p  = rp[wid] + part[wid >> 10];
  int p1 = rp[wid + 1] + part[(wid + 1) >> 10];
  for (; p + 8 <= p1; p += 8) {
    int s[8];
#pragma unroll
    for (int u = 0; u < 8; u++) s[u] = srcs[p + u];
    float w[8];
#pragma unroll
    for (int u = 0; u < 8; u++) w[u] = dinv[s[u]] * invd;
    if (VPL == 4) {
      ushort4 h[8];
#pragma unroll
      for (int u = 0; u < 8; u++) h[u] = *(const ushort4*)(Hf + (size_t)s[u] * F);
#pragma unroll
      for (int u = 0; u < 8; u++) {
        acc[0] += w[u] * b2f(h[u].x); acc[1] += w[u] * b2f(h[u].y);
        acc[2] += w[u] * b2f(h[u].z); acc[3] += w[u] * b2f(h[u].w);
      }
    } else {
      ushort2 h[8];
#pragma unroll
      for (int u = 0; u < 8; u++) h[u] = *(const ushort2*)(Hf + (size_t)s[u] * F);
#pragma unroll
      for (int u = 0; u < 8; u++) {
        acc[0] += w[u] * b2f(h[u].x); acc[1] += w[u] * b2f(h[u].y);
      }
    }
  }
  for (; p < p1; ++p) {
    int s = srcs[p];
    float w = dinv[s] * invd;
    if (VPL == 4) {
      ushort4 hv = *(const ushort4*)(Hf + (size_t)s * F);
      acc[0] += w * b2f(hv.x); acc[1] += w * b2f(hv.y);
      acc[2] += w * b2f(hv.z); acc[3] += w * b2f(hv.w);
    } else {
      ushort2 hv = *(const ushort2*)(Hf + (size_t)s * F);
      acc[0] += w * b2f(hv.x); acc[1] += w * b2f(hv.y);
    }
  }
  ushort* op = out + (size_t)wid * F + fo;
#pragma unroll
  for (int v = 0; v < VPL; v++) op[v] = f2b(fmaxf(acc[v], 0.0f));
}

// ---------------- launch ----------------

extern "C" void kernel_launch(void* const* d_in, const int* in_sizes, int n_in,
                              void* d_out, int out_size, void* d_ws, size_t ws_size,
                              hipStream_t stream) {
  const float* x  = (const float*)d_in[0];   // f32 per reference dtypes
  const int* ei   = (const int*)d_in[1];
  const float* W1 = (const float*)d_in[2];
  const float* b1 = (const float*)d_in[3];
  const float* W2 = (const float*)d_in[4];
  const float* b2 = (const float*)d_in[5];
  const float* Wc = (const float*)d_in[6];
  const float* bc = (const float*)d_in[7];

  const int N = in_sizes[0] / F_IN;
  const int E = in_sizes[1] / 2;
  const int* e_src = ei;
  const int* e_dst = ei + E;

  // workspace layout (256B aligned slices); total ~55.3 MB
  char* ws = (char*)d_ws;
  size_t off = 0;
  auto alloc = [&](size_t bytes) { char* p = ws + off; off += (bytes + 255) & ~(size_t)255; return p; };
  int*    cnt  = (int*)alloc((size_t)N * 4);
  float*  dinv = (float*)alloc((size_t)N * 4);
  int*    rp   = (int*)alloc((size_t)(N + 1) * 4);
  int*    part = (int*)alloc((size_t)1024 * 4);
  int*    srcs = (int*)alloc((size_t)E * 4);
  ushort* w1t  = (ushort*)alloc((size_t)F_HID * F_IN * 2);
  ushort* w2t  = (ushort*)alloc((size_t)F_MID * F_HID * 2);
  ushort* wct  = (ushort*)alloc((size_t)F_OUT * F_MID * 2);
  ushort* bufH = (ushort*)alloc((size_t)N * F_HID * 2);  // pre-agg H
  ushort* bufG = (ushort*)alloc((size_t)N * F_HID * 2);  // post-agg h
  (void)ws_size; (void)n_in; (void)out_size;

  int gE = (E + 255) / 256, gW = (N + 3) / 4;
  int gM256 = (N + 255) / 256;
  int nb = (N + 1023) / 1024;
  int trN = (F_IN * F_HID + F_HID * F_MID + F_MID * F_OUT + 255) / 256;

  // CSR + dinv (dinv fused into scan1; scan3 folded into fill/agg via part[])
  hipMemsetAsync(cnt, 0, (size_t)N * 4, stream);
  hist_kernel<<<gE, 256, 0, stream>>>(e_dst, cnt, E);
  scan1_kernel<<<nb, 1024, 0, stream>>>(cnt, rp, part, dinv, N);
  scan2_kernel<<<1, 1024, 0, stream>>>(part, nb);
  fill_kernel<<<gE, 256, 0, stream>>>(e_src, e_dst, rp, part, cnt, srcs, E);

  // all weight transposes in one launch
  transpose_all<<<trN, 256, 0, stream>>>(W1, W2, Wc, w1t, w2t, wct);

  // layer 1: H = x @ W1 (f32 A, register-direct GEMM) ; h1 = relu(agg(H) + b1)
  gemm_reg<512, true, false, false><<<dim3(gM256, F_HID / 64), 256, 0, stream>>>(x, w1t, nullptr, bufH, N, F_HID);
  agg_kernel<F_HID><<<gW, 256, 0, stream>>>(bufH, b1, dinv, rp, part, srcs, bufG, N);

  // layer 2: H2 = h1 @ W2 ; h2 = relu(agg(H2) + b2)
  gemm_reg<256, false, false, false><<<dim3(gM256, F_MID / 64), 256, 0, stream>>>(bufG, w2t, nullptr, bufH, N, F_MID);
  agg_kernel<F_MID><<<gW, 256, 0, stream>>>(bufH, b2, dinv, rp, part, srcs, bufG, N);

  // classifier + log_softmax fused: d_out = log_softmax(h2 @ Wc + bc), f32
  gemm_reg<128, false, true, true><<<dim3(gM256, 1), 256, 0, stream>>>(bufG, wct, bc, d_out, N, F_OUT);
}